// Round 1
// baseline (685.951 us; speedup 1.0000x reference)
//
#include <hip/hip_runtime.h>
#include <stdint.h>

#define H_DIM 1024
#define E_NUM 8
#define FF_DIM 4096
#define T_TOK 4096   // B*S = 2*2048

typedef __bf16 bf16x8 __attribute__((ext_vector_type(8)));
typedef float f32x4 __attribute__((ext_vector_type(4)));

__device__ __forceinline__ unsigned short f2bf(float f) {
  union { float f; uint32_t u; } v; v.f = f;
  uint32_t u = v.u;
  uint32_t r = u + 0x7fffu + ((u >> 16) & 1u);   // RNE
  return (unsigned short)(r >> 16);
}

__device__ __forceinline__ float geluf(float x) {
  return 0.5f * x * (1.0f + erff(x * 0.70710678118654752f));
}

// ---------------- gating ----------------
__global__ __launch_bounds__(64) void gate_kernel(
    const float* __restrict__ x, const float* __restrict__ gw, const float* __restrict__ gb,
    int* __restrict__ topidx, float* __restrict__ topw, int* __restrict__ counts) {
  int t = blockIdx.x;
  int l = threadIdx.x;
  const float* xt = x + (size_t)t * H_DIM;
  float acc[E_NUM];
  #pragma unroll
  for (int e = 0; e < E_NUM; e++) acc[e] = 0.f;
  for (int k = l; k < H_DIM; k += 64) {
    float xv = xt[k];
    #pragma unroll
    for (int e = 0; e < E_NUM; e++) acc[e] += xv * gw[e * H_DIM + k];
  }
  #pragma unroll
  for (int e = 0; e < E_NUM; e++) {
    float v = acc[e];
    #pragma unroll
    for (int off = 32; off > 0; off >>= 1) v += __shfl_xor(v, off, 64);
    acc[e] = v;
  }
  if (l == 0) {
    float s[E_NUM];
    #pragma unroll
    for (int e = 0; e < E_NUM; e++) s[e] = 1.f / (1.f + expf(-(acc[e] + gb[e])));
    int i1 = 0; float v1 = s[0];
    #pragma unroll
    for (int e = 1; e < E_NUM; e++) if (s[e] > v1) { v1 = s[e]; i1 = e; }
    int i2 = -1; float v2 = -1.f;
    #pragma unroll
    for (int e = 0; e < E_NUM; e++) if (e != i1 && s[e] > v2) { v2 = s[e]; i2 = e; }
    float denom = v1 + v2 + 1e-6f;
    topidx[t * 2]     = i1; topidx[t * 2 + 1] = i2;
    topw[t * 2]       = v1 / denom;
    topw[t * 2 + 1]   = v2 / denom;
    atomicAdd(&counts[i1], 1);
    atomicAdd(&counts[i2], 1);
  }
}

__global__ void init_kernel(int* counts) {
  if (threadIdx.x < E_NUM) counts[threadIdx.x] = 0;
}

__global__ void scan_kernel(const int* __restrict__ counts, int* __restrict__ offs,
                            int* __restrict__ cursor) {
  if (threadIdx.x == 0) {
    int a = 0;
    for (int e = 0; e < E_NUM; e++) { offs[e] = a; a += counts[e]; cursor[e] = 0; }
    offs[E_NUM] = a;   // == 2*T_TOK
  }
}

__global__ void dispatch_kernel(const int* __restrict__ topidx, const float* __restrict__ topw,
                                const int* __restrict__ offs, int* __restrict__ cursor,
                                int* __restrict__ gidx, float* __restrict__ gwt) {
  int t = blockIdx.x * blockDim.x + threadIdx.x;
  if (t >= T_TOK) return;
  #pragma unroll
  for (int j = 0; j < 2; j++) {
    int ex  = topidx[t * 2 + j];
    int pos = atomicAdd(&cursor[ex], 1);
    int slot = offs[ex] + pos;
    gidx[slot] = t;
    gwt[slot]  = topw[t * 2 + j];
  }
}

// ---------------- casts ----------------
__global__ __launch_bounds__(256) void cast_x_kernel(const float* __restrict__ x,
                                                     unsigned short* __restrict__ xb) {
  int i = blockIdx.x * blockDim.x + threadIdx.x;   // covers T*H/4
  float4 v = ((const float4*)x)[i];
  ushort4 o;
  o.x = f2bf(v.x); o.y = f2bf(v.y); o.z = f2bf(v.z); o.w = f2bf(v.w);
  ((ushort4*)xb)[i] = o;
}

// in: [batch][R][C] f32  ->  out: [batch][C][R] bf16
__global__ __launch_bounds__(256) void transpose_cast_kernel(
    const float* __restrict__ in, unsigned short* __restrict__ out, int R, int C) {
  __shared__ float tile[32][33];
  const size_t bo = (size_t)blockIdx.z * (size_t)R * C;
  const float* inb = in + bo;
  unsigned short* outb = out + bo;
  int c0 = blockIdx.x * 32, r0 = blockIdx.y * 32;
  int tx = threadIdx.x & 31, ty = threadIdx.x >> 5;   // 32 x 8
  #pragma unroll
  for (int i = 0; i < 32; i += 8)
    tile[ty + i][tx] = inb[(size_t)(r0 + ty + i) * C + (c0 + tx)];
  __syncthreads();
  #pragma unroll
  for (int i = 0; i < 32; i += 8)
    outb[(size_t)(c0 + ty + i) * R + (r0 + tx)] = f2bf(tile[tx][ty + i]);
}

// ---------------- GEMM ----------------
// 128x128 tile, BK=64, 4 waves each 64x64 (4x4 of 16x16x32 MFMA).
// LDS layout: [128 rows][64 bf16] with 16B-unit XOR swizzle u' = u ^ (r&7).
// Staged via global_load_lds (linear LDS dest, pre-swizzled global source).
template <bool FFN1, bool ROUTED>
__global__ __launch_bounds__(256) void gemm_kernel(
    const unsigned short* __restrict__ A,    // bf16 [M][K]   (xb or hdn)
    const unsigned short* __restrict__ Bt,   // bf16 [E?][N][K] (transposed weight)
    const float* __restrict__ bias,          // [E?][N]
    void* __restrict__ outp,                 // FFN1: bf16 hdn[slots][N]; FFN2: f32 out[T][N]
    const int* __restrict__ gidx, const float* __restrict__ gwt,
    const int* __restrict__ offs,            // [E+1] (ROUTED only)
    int K, int N) {
  __shared__ __align__(16) char ldsA[128 * 128];
  __shared__ __align__(16) char ldsB[128 * 128];
  __shared__ int tokLds[128];
  __shared__ float wLds[128];

  const int tid = threadIdx.x;
  const int w = tid >> 6;
  const int l = tid & 63;
  const int e = ROUTED ? blockIdx.z : 0;
  const int n0 = blockIdx.x * 128;

  int base_slot, rows_valid;
  if (ROUTED) {
    int o0 = offs[e], o1 = offs[e + 1];
    int cnt = o1 - o0;
    int m0 = blockIdx.y * 128;
    if (m0 >= cnt) return;
    base_slot = o0 + m0;
    rows_valid = min(128, cnt - m0);
  } else {
    base_slot = blockIdx.y * 128;
    rows_valid = 128;
  }

  if (tid < 128) {
    int tk;
    if (ROUTED) tk = gidx[base_slot + min(tid, rows_valid - 1)];
    else        tk = base_slot + tid;
    tokLds[tid] = tk;
    if (ROUTED && !FFN1) wLds[tid] = (tid < rows_valid) ? gwt[base_slot + tid] : 0.f;
  }
  __syncthreads();

  const int lr = l >> 3;             // row within 8-row staging group
  const int su = (l & 7) ^ lr;       // pre-swizzled source 16B-unit
  const unsigned short* aSrc[4];
  const unsigned short* bSrc[4];
  const unsigned short* BtE = Bt + (size_t)e * (size_t)N * K;
  #pragma unroll
  for (int i = 0; i < 4; i++) {
    int r = w * 32 + i * 8 + lr;
    size_t arow;
    if (FFN1) arow = (size_t)tokLds[r] * K;          // gathered token rows
    else      arow = (size_t)(base_slot + r) * K;    // compact hdn rows
    aSrc[i] = A + arow + su * 8;
    int nr = n0 + w * 32 + i * 8 + lr;
    bSrc[i] = BtE + (size_t)nr * K + su * 8;
  }
  char* aDst[4];
  char* bDst[4];
  #pragma unroll
  for (int i = 0; i < 4; i++) {
    aDst[i] = ldsA + (w * 32 + i * 8) * 128;
    bDst[i] = ldsB + (w * 32 + i * 8) * 128;
  }

  f32x4 acc[4][4];
  #pragma unroll
  for (int m = 0; m < 4; m++)
    #pragma unroll
    for (int n = 0; n < 4; n++) acc[m][n] = (f32x4){0.f, 0.f, 0.f, 0.f};

  const int wr = w >> 1, wc = w & 1;

  for (int kt = 0; kt < K; kt += 64) {
    #pragma unroll
    for (int i = 0; i < 4; i++)
      __builtin_amdgcn_global_load_lds(
          (const __attribute__((address_space(1))) void*)(aSrc[i] + kt),
          (__attribute__((address_space(3))) void*)aDst[i], 16, 0, 0);
    #pragma unroll
    for (int i = 0; i < 4; i++)
      __builtin_amdgcn_global_load_lds(
          (const __attribute__((address_space(1))) void*)(bSrc[i] + kt),
          (__attribute__((address_space(3))) void*)bDst[i], 16, 0, 0);
    __syncthreads();   // drains vmcnt before barrier
    #pragma unroll
    for (int kk = 0; kk < 2; kk++) {
      bf16x8 af[4], bfr[4];
      #pragma unroll
      for (int m = 0; m < 4; m++) {
        int r = wr * 64 + m * 16 + (l & 15);
        int u = (kk * 4 + (l >> 4)) ^ (l & 7);     // r&7 == l&7
        af[m] = *(const bf16x8*)(ldsA + r * 128 + u * 16);
      }
      #pragma unroll
      for (int n = 0; n < 4; n++) {
        int r = wc * 64 + n * 16 + (l & 15);
        int u = (kk * 4 + (l >> 4)) ^ (l & 7);
        bfr[n] = *(const bf16x8*)(ldsB + r * 128 + u * 16);
      }
      #pragma unroll
      for (int m = 0; m < 4; m++)
        #pragma unroll
        for (int n = 0; n < 4; n++)
          acc[m][n] = __builtin_amdgcn_mfma_f32_16x16x32_bf16(af[m], bfr[n], acc[m][n], 0, 0, 0);
    }
    __syncthreads();
  }

  // epilogue: C/D layout col = l&15, row = (l>>4)*4 + j
  const float* biasE = bias + (size_t)e * N;
  const int cc = l & 15;
  #pragma unroll
  for (int m = 0; m < 4; m++) {
    #pragma unroll
    for (int n = 0; n < 4; n++) {
      int col = n0 + wc * 64 + n * 16 + cc;
      float b = biasE[col];
      #pragma unroll
      for (int j = 0; j < 4; j++) {
        int rloc = wr * 64 + m * 16 + (l >> 4) * 4 + j;
        if (rloc < rows_valid) {
          float v = acc[m][n][j] + b;
          if (FFN1) {
            v = geluf(v);
            ((unsigned short*)outp)[(size_t)(base_slot + rloc) * N + col] = f2bf(v);
          } else if (ROUTED) {
            atomicAdd(&((float*)outp)[(size_t)tokLds[rloc] * N + col], v * wLds[rloc]);
          } else {
            ((float*)outp)[(size_t)(base_slot + rloc) * N + col] = v * 0.1f;
          }
        }
      }
    }
  }
}

// ---------------- host ----------------
extern "C" void kernel_launch(void* const* d_in, const int* in_sizes, int n_in,
                              void* d_out, int out_size, void* d_ws, size_t ws_size,
                              hipStream_t stream) {
  const float* x   = (const float*)d_in[0];
  const float* gw  = (const float*)d_in[1];
  const float* gb  = (const float*)d_in[2];
  const float* w1  = (const float*)d_in[3];
  const float* b1  = (const float*)d_in[4];
  const float* w2  = (const float*)d_in[5];
  const float* b2  = (const float*)d_in[6];
  const float* sw1 = (const float*)d_in[7];
  const float* sb1 = (const float*)d_in[8];
  const float* sw2 = (const float*)d_in[9];
  const float* sb2 = (const float*)d_in[10];
  float* out = (float*)d_out;

  char* p = (char*)d_ws;
  auto alloc = [&](size_t bytes) {
    char* r = p;
    p += (bytes + 255) & ~(size_t)255;
    return r;
  };
  int*   counts = (int*)alloc(E_NUM * 4);
  int*   cursor = (int*)alloc(E_NUM * 4);
  int*   offs   = (int*)alloc((E_NUM + 1) * 4);
  int*   topidx = (int*)alloc((size_t)T_TOK * 2 * 4);
  float* topw   = (float*)alloc((size_t)T_TOK * 2 * 4);
  int*   gidx   = (int*)alloc((size_t)2 * T_TOK * 4);
  float* gwt    = (float*)alloc((size_t)2 * T_TOK * 4);
  unsigned short* xb   = (unsigned short*)alloc((size_t)T_TOK * H_DIM * 2);
  unsigned short* w1t  = (unsigned short*)alloc((size_t)E_NUM * FF_DIM * H_DIM * 2);
  unsigned short* w2t  = (unsigned short*)alloc((size_t)E_NUM * H_DIM * FF_DIM * 2);
  unsigned short* sw1t = (unsigned short*)alloc((size_t)FF_DIM * H_DIM * 2);
  unsigned short* sw2t = (unsigned short*)alloc((size_t)H_DIM * FF_DIM * 2);
  unsigned short* hdnR = (unsigned short*)alloc((size_t)(2 * T_TOK + 128) * FF_DIM * 2); // +128 pad rows
  unsigned short* hdnS = (unsigned short*)alloc((size_t)T_TOK * FF_DIM * 2);

  // routing
  init_kernel<<<1, 64, 0, stream>>>(counts);
  gate_kernel<<<T_TOK, 64, 0, stream>>>(x, gw, gb, topidx, topw, counts);
  scan_kernel<<<1, 1, 0, stream>>>(counts, offs, cursor);
  dispatch_kernel<<<T_TOK / 256, 256, 0, stream>>>(topidx, topw, offs, cursor, gidx, gwt);

  // precision conversion / weight transpose (f32 -> bf16, [K][N] -> [N][K])
  cast_x_kernel<<<(T_TOK * H_DIM / 4) / 256, 256, 0, stream>>>(x, xb);
  transpose_cast_kernel<<<dim3(FF_DIM / 32, H_DIM / 32, E_NUM), 256, 0, stream>>>(w1, w1t, H_DIM, FF_DIM);
  transpose_cast_kernel<<<dim3(H_DIM / 32, FF_DIM / 32, E_NUM), 256, 0, stream>>>(w2, w2t, FF_DIM, H_DIM);
  transpose_cast_kernel<<<dim3(FF_DIM / 32, H_DIM / 32, 1), 256, 0, stream>>>(sw1, sw1t, H_DIM, FF_DIM);
  transpose_cast_kernel<<<dim3(H_DIM / 32, FF_DIM / 32, 1), 256, 0, stream>>>(sw2, sw2t, FF_DIM, H_DIM);

  // shared expert (FFN2 plain-stores => initializes out)
  gemm_kernel<true, false><<<dim3(FF_DIM / 128, T_TOK / 128, 1), 256, 0, stream>>>(
      xb, sw1t, sb1, hdnS, nullptr, nullptr, nullptr, H_DIM, FF_DIM);
  gemm_kernel<false, false><<<dim3(H_DIM / 128, T_TOK / 128, 1), 256, 0, stream>>>(
      hdnS, sw2t, sb2, out, nullptr, nullptr, nullptr, FF_DIM, H_DIM);

  // routed experts (FFN2 atomic-adds on top of shared output)
  gemm_kernel<true, true><<<dim3(FF_DIM / 128, T_TOK / 128, E_NUM), 256, 0, stream>>>(
      xb, w1t, b1, hdnR, gidx, gwt, offs, H_DIM, FF_DIM);
  gemm_kernel<false, true><<<dim3(H_DIM / 128, T_TOK / 128, E_NUM), 256, 0, stream>>>(
      hdnR, w2t, b2, out, gidx, gwt, offs, FF_DIM, H_DIM);
}